// Round 12
// baseline (38.674 us; speedup 1.0000x reference)
//
#include <hip/hip_runtime.h>
#include <climits>

#define HH 1024
#define WW 1024
#define DD 128
#define NPIX (HH * WW)
#define NSB 256    // stats blocks (4 rows each)
#define NBB 512    // main blocks (2 rows each)

// ws 4B-unit layout:
//   wsf[64..576)    M (4x128 row-major)
//   wsf[576..704)   c (128)
//   wsf[704..832)   m (mean hidden, by kC1)
//   wsi[1024..1280) rminP | [1280..1536) rmaxP | [1536..1792) cminP
//   wsi[1792..2048) cmaxP | [2048..2304) cntP     (one per stats block)
//   wsf[6200..6456) warm-read dummies
//   wsf[8192..8192+128*512) partials, layout [feature][block]
#define RMINP 1024
#define RMAXP 1280
#define CMINP 1536
#define CMAXP 1792
#define CNTP  2048
#define MOFF  704
#define PART  8192

typedef _Float16 f16;
typedef __attribute__((ext_vector_type(8)))  _Float16 f16x8;
typedef __attribute__((ext_vector_type(16))) float    f32x16;

// ---- stats for a block's 4 rows (proven rounds 4-11) -----------------------
__device__ __forceinline__ void d_stats(const float* __restrict__ x0, int blk,
                                        int tid, int* __restrict__ wsi,
                                        int (*sred)[8]) {
    const float4* x4 = (const float4*)(x0) + (size_t)blk * 1024;
    int any0, any1, any2, any3;
    int cmn = INT_MAX, cmx = -1, cnt = 0;
    int c4 = 4 * tid;
    {
        float4 v;
        bool z0, z1, z2, z3;
        #define STAT_K(K, ANY)                                                 \
            v = x4[K * 256 + tid];                                             \
            z0 = v.x != 0.f; z1 = v.y != 0.f; z2 = v.z != 0.f; z3 = v.w != 0.f;\
            ANY = (int)(z0 | z1 | z2 | z3);                                    \
            if (ANY) {                                                         \
                cmn = min(cmn, z0 ? c4 : (z1 ? c4+1 : (z2 ? c4+2 : c4+3)));    \
                cmx = max(cmx, z3 ? c4+3 : (z2 ? c4+2 : (z1 ? c4+1 : c4)));    \
            }                                                                  \
            cnt += (int)z0 + (int)z1 + (int)z2 + (int)z3;
        STAT_K(0, any0) STAT_K(1, any1) STAT_K(2, any2) STAT_K(3, any3)
        #undef STAT_K
    }
    for (int off = 32; off >= 1; off >>= 1) {
        cmn = min(cmn, __shfl_xor(cmn, off, 64));
        cmx = max(cmx, __shfl_xor(cmx, off, 64));
        cnt += __shfl_xor(cnt, off, 64);
        any0 |= __shfl_xor(any0, off, 64);
        any1 |= __shfl_xor(any1, off, 64);
        any2 |= __shfl_xor(any2, off, 64);
        any3 |= __shfl_xor(any3, off, 64);
    }
    int wave = tid >> 6;
    if ((tid & 63) == 0) {
        sred[wave][0] = cmn; sred[wave][1] = cmx; sred[wave][2] = cnt;
        sred[wave][3] = any0; sred[wave][4] = any1;
        sred[wave][5] = any2; sred[wave][6] = any3;
    }
    __syncthreads();
    if (tid == 0) {
        int a = sred[0][0], b = sred[0][1], c = sred[0][2];
        int f0 = sred[0][3], f1 = sred[0][4], f2 = sred[0][5], f3 = sred[0][6];
        for (int w = 1; w < 4; ++w) {
            a = min(a, sred[w][0]); b = max(b, sred[w][1]); c += sred[w][2];
            f0 |= sred[w][3]; f1 |= sred[w][4]; f2 |= sred[w][5]; f3 |= sred[w][6];
        }
        int r0 = blk * 4;
        wsi[RMINP + blk] = f0 ? r0 : (f1 ? r0+1 : (f2 ? r0+2 : (f3 ? r0+3 : INT_MAX)));
        wsi[RMAXP + blk] = f3 ? r0+3 : (f2 ? r0+2 : (f1 ? r0+1 : (f0 ? r0 : -1)));
        wsi[CMINP + blk] = a;
        wsi[CMAXP + blk] = b;
        wsi[CNTP  + blk] = c;
    }
}

// ---- kA: 256 stats blocks + 1 prep block (M, c; warm W3 into L3) -----------
__global__ __launch_bounds__(256) void kA(const float* __restrict__ x0,
                                          const float* __restrict__ W1,
                                          const float* __restrict__ b1,
                                          const float* __restrict__ W2,
                                          const float* __restrict__ b2,
                                          const float* __restrict__ W3,
                                          float* __restrict__ wsf,
                                          int* __restrict__ wsi) {
    __shared__ int sred[4][8];
    int blk = blockIdx.x, tid = threadIdx.x;
    if (blk < NSB) { d_stats(x0, blk, tid, wsi, sred); return; }
    if (tid < 128) {
        int j = tid;
        float p0 = 0.f, p1 = 0.f, p2 = 0.f, p3 = 0.f, cc = 0.f;
        #pragma unroll 8
        for (int d = 0; d < DD; ++d) {
            float w2 = W2[d * DD + j];
            p0 = fmaf(W1[0 * DD + d], w2, p0);
            p1 = fmaf(W1[1 * DD + d], w2, p1);
            p2 = fmaf(W1[2 * DD + d], w2, p2);
            p3 = fmaf(W1[3 * DD + d], w2, p3);
            cc = fmaf(b1[d],          w2, cc);
        }
        wsf[64 + 0 * DD + j] = p0;
        wsf[64 + 1 * DD + j] = p1;
        wsf[64 + 2 * DD + j] = p2;
        wsf[64 + 3 * DD + j] = p3;
        wsf[576 + j] = cc + b2[j];
    } else {
        // warm W3 into L3 for kC2's single-block matvec
        const float4* w34 = (const float4*)W3;
        float s = 0.f;
        for (int k = tid - 128; k < DD * DD / 4; k += 128) {
            float4 t4 = w34[k]; s += t4.x + t4.y + t4.z + t4.w;
        }
        wsf[6200 + tid - 128] = s;   // keep warm loads alive
    }
}

// ---- kB: MFMA main accumulate (round-6-proven). 2 rows/block ---------------
// Wave w: row = 2*blk + (w>>1), col half = (w&1)*512. Lane<32 owns pixel
// col = colbase + t*32 + (lane&31). A k-slots (f16): (v0, v1, dcol, 0...);
// B k-slots: (M2[j], M3[j], a1h[j], 0...); C = cp + a0*row + a1*colbase (f32).
__global__ __launch_bounds__(256) void kB(const float* __restrict__ x0,
                                          const float* __restrict__ x1,
                                          float* __restrict__ wsf,
                                          const int* __restrict__ wsi) {
    __shared__ float lred[4][128];
    __shared__ int   sred[4][4];
    __shared__ int   zlist[2048];
    __shared__ int   zcnt;

    int tid = threadIdx.x, blk = blockIdx.x;
    int lane = tid & 63, wv = tid >> 6;
    bool lo = lane < 32;
    int j32 = lane & 31;

    if (tid == 0) zcnt = 0;

    // reduce the 256 stats partials
    int rmn = wsi[RMINP + tid], rmx = wsi[RMAXP + tid];
    int cmn = wsi[CMINP + tid], cmx = wsi[CMAXP + tid];
    for (int off = 32; off >= 1; off >>= 1) {
        rmn = min(rmn, __shfl_xor(rmn, off, 64));
        rmx = max(rmx, __shfl_xor(rmx, off, 64));
        cmn = min(cmn, __shfl_xor(cmn, off, 64));
        cmx = max(cmx, __shfl_xor(cmx, off, 64));
    }
    if ((tid & 63) == 0) {
        sred[wv][0] = rmn; sred[wv][1] = rmx;
        sred[wv][2] = cmn; sred[wv][3] = cmx;
    }
    __syncthreads();   // sred + zcnt visible
    rmn = min(min(sred[0][0], sred[1][0]), min(sred[2][0], sred[3][0]));
    rmx = max(max(sred[0][1], sred[1][1]), max(sred[2][1], sred[3][1]));
    cmn = min(min(sred[0][2], sred[1][2]), min(sred[2][2], sred[3][2]));
    cmx = max(max(sred[0][3], sred[1][3]), max(sred[2][3], sred[3][3]));

    float rs = 1.0f / (float)(rmx - rmn);
    float cs = 1.0f / (float)(cmx - cmn);
    int row = blk * 2 + (wv >> 1);
    int colbase = (wv & 1) * 512;

    // per-j-tile fragments
    f16x8 B0, B1, B2, B3;
    f32x16 C0, C1, C2, C3;
    float a1r0, a1r1, a1r2, a1r3;
    #define MKJT(JT, BV, CV, A1R) {                                            \
        int idx = JT * 32 + j32;                                               \
        float M2f = wsf[64 + 2 * DD + idx];                                    \
        float M3f = wsf[64 + 3 * DD + idx];                                    \
        float a0f = wsf[64 + 0 * DD + idx] * rs;                               \
        float a1f = wsf[64 + 1 * DD + idx] * cs;                               \
        float cpf = wsf[576 + idx] - (float)rmn * a0f - (float)cmn * a1f;      \
        float cval = fmaf(a0f, (float)row, fmaf(a1f, (float)colbase, cpf));    \
        f16 a1h = (f16)a1f;  A1R = (float)a1h;                                 \
        _Float16 z = (_Float16)0.f;                                            \
        BV[0] = z; BV[1] = z; BV[2] = z; BV[3] = z;                            \
        BV[4] = z; BV[5] = z; BV[6] = z; BV[7] = z;                            \
        if (lo) { BV[0] = (f16)M2f; BV[1] = (f16)M3f; BV[2] = a1h; }           \
        _Pragma("unroll")                                                      \
        for (int i = 0; i < 16; ++i) CV[i] = cval; }
    MKJT(0, B0, C0, a1r0)
    MKJT(1, B1, C1, a1r1)
    MKJT(2, B2, C2, a1r2)
    MKJT(3, B3, C3, a1r3)
    #undef MKJT

    const float* p0 = x0 + (size_t)row * WW + colbase + j32;
    const float* p1 = x1 + (size_t)row * WW + colbase + j32;
    float acc0 = 0.f, acc1 = 0.f, acc2 = 0.f, acc3 = 0.f;
    float j32f = (float)j32;

    f16x8 A;
    {
        _Float16 z = (_Float16)0.f;
        #pragma unroll
        for (int i = 0; i < 8; ++i) A[i] = z;
    }

    #pragma unroll 2
    for (int t = 0; t < 16; ++t) {
        float v0f = 0.f, v1f = 0.f;
        if (lo) { v0f = p0[t * 32]; v1f = p1[t * 32]; }
        if (lo && v0f == 0.f) {   // masked-out pixel (rare): remember it
            int q = atomicAdd(&zcnt, 1);
            zlist[q] = ((wv >> 1) << 12) | (colbase + t * 32 + j32);
        }
        if (lo) {
            A[0] = (f16)v0f;
            A[1] = (f16)v1f;
            A[2] = (f16)(j32f + (float)(t * 32));   // dcol, f16-exact (<512)
        }
        f32x16 D;
        D = __builtin_amdgcn_mfma_f32_32x32x16_f16(A, B0, C0, 0, 0, 0);
        #pragma unroll
        for (int i = 0; i < 16; ++i) acc0 += fmaxf(D[i], 0.f);
        D = __builtin_amdgcn_mfma_f32_32x32x16_f16(A, B1, C1, 0, 0, 0);
        #pragma unroll
        for (int i = 0; i < 16; ++i) acc1 += fmaxf(D[i], 0.f);
        D = __builtin_amdgcn_mfma_f32_32x32x16_f16(A, B2, C2, 0, 0, 0);
        #pragma unroll
        for (int i = 0; i < 16; ++i) acc2 += fmaxf(D[i], 0.f);
        D = __builtin_amdgcn_mfma_f32_32x32x16_f16(A, B3, C3, 0, 0, 0);
        #pragma unroll
        for (int i = 0; i < 16; ++i) acc3 += fmaxf(D[i], 0.f);
    }

    // subtract masked-out pixels' relu(a1h*dcol + cval) contributions
    __syncthreads();   // zlist complete
    int nz = zcnt;
    int hsel = lane >> 5;
    for (int ii = 0; ii < nz; ++ii) {
        int pc = zlist[ii];
        int zrbit = pc >> 12;
        int zc = pc & 4095;
        if (zrbit == (wv >> 1) && (zc >> 9) == (wv & 1) &&
            (((zc >> 2) & 1) == hsel)) {
            float dcolf = (float)(zc - colbase);
            float t0 = fmaf(a1r0, dcolf, C0[0]); acc0 -= fmaxf(t0, 0.f);
            float t1 = fmaf(a1r1, dcolf, C1[0]); acc1 -= fmaxf(t1, 0.f);
            float t2 = fmaf(a1r2, dcolf, C2[0]); acc2 -= fmaxf(t2, 0.f);
            float t3 = fmaf(a1r3, dcolf, C3[0]); acc3 -= fmaxf(t3, 0.f);
        }
    }

    // combine lane halves (same j, disjoint pixel rows), then waves
    acc0 += __shfl_xor(acc0, 32, 64);
    acc1 += __shfl_xor(acc1, 32, 64);
    acc2 += __shfl_xor(acc2, 32, 64);
    acc3 += __shfl_xor(acc3, 32, 64);
    if (lo) {
        lred[wv][0 * 32 + j32] = acc0;
        lred[wv][1 * 32 + j32] = acc1;
        lred[wv][2 * 32 + j32] = acc2;
        lred[wv][3 * 32 + j32] = acc3;
    }
    __syncthreads();
    if (tid < 128) {
        float s = lred[0][tid] + lred[1][tid] + lred[2][tid] + lred[3][tid];
        wsf[PART + (size_t)tid * NBB + blk] = s;
    }
}

// ---- kC1: 128 blocks, one feature each: sum partials + count -> m[f] -------
__global__ __launch_bounds__(256) void kC1(float* __restrict__ wsf,
                                           const int* __restrict__ wsi) {
    __shared__ float sred[4];
    __shared__ int   cred[4];
    int f = blockIdx.x, tid = threadIdx.x;
    int wv = tid >> 6, lane = tid & 63;

    // total mask count (256 per-stats-block counts)
    int c = wsi[CNTP + tid];
    for (int off = 32; off >= 1; off >>= 1) c += __shfl_xor(c, off, 64);
    if (lane == 0) cred[wv] = c;

    // per-feature sum over 512 block-partials (contiguous -> coalesced)
    const float* p = wsf + PART + (size_t)f * NBB;
    float S = p[tid] + p[tid + 256];
    for (int off = 32; off >= 1; off >>= 1) S += __shfl_xor(S, off, 64);
    if (lane == 0) sred[wv] = S;
    __syncthreads();
    if (tid == 0) {
        float tot = (sred[0] + sred[1]) + (sred[2] + sred[3]);
        float cnt = (float)(cred[0] + cred[1] + cred[2] + cred[3]);
        wsf[MOFF + f] = tot / cnt;
    }
}

// ---- kC2: 1 block, 256 threads: out = b3 + m @ W3 (coalesced row reads) ----
__global__ __launch_bounds__(256) void kC2(const float* __restrict__ wsf,
                                           const float* __restrict__ W3,
                                           const float* __restrict__ b3,
                                           float* __restrict__ out) {
    __shared__ float sm[128];
    __shared__ float s2[256];
    int tid = threadIdx.x;
    if (tid < 128) sm[tid] = wsf[MOFF + tid];
    __syncthreads();

    int col = tid & 127, h = tid >> 7;
    float o = 0.f;
    #pragma unroll 8
    for (int d = h * 64; d < h * 64 + 64; ++d)
        o = fmaf(sm[d], W3[d * DD + col], o);   // per-d coalesced across lanes
    s2[tid] = o;
    __syncthreads();
    if (tid < 128) out[tid] = b3[tid] + s2[tid] + s2[tid + 128];
}

extern "C" void kernel_launch(void* const* d_in, const int* in_sizes, int n_in,
                              void* d_out, int out_size, void* d_ws, size_t ws_size,
                              hipStream_t stream) {
    const float* x  = (const float*)d_in[0];
    const float* x0 = x;
    const float* x1 = x + NPIX;
    const float* W1 = (const float*)d_in[1];
    const float* b1 = (const float*)d_in[2];
    const float* W2 = (const float*)d_in[3];
    const float* b2 = (const float*)d_in[4];
    const float* W3 = (const float*)d_in[5];
    const float* b3 = (const float*)d_in[6];
    float* outp = (float*)d_out;
    float* wsf  = (float*)d_ws;
    int*   wsi  = (int*)d_ws;

    hipLaunchKernelGGL(kA, dim3(NSB + 1), dim3(256), 0, stream,
                       x0, W1, b1, W2, b2, W3, wsf, wsi);
    hipLaunchKernelGGL(kB, dim3(NBB), dim3(256), 0, stream, x0, x1, wsf, wsi);
    hipLaunchKernelGGL(kC1, dim3(DD), dim3(256), 0, stream, wsf, wsi);
    hipLaunchKernelGGL(kC2, dim3(1), dim3(256), 0, stream, wsf, W3, b3, outp);
}

// Round 13
// 36.741 us; speedup vs baseline: 1.0526x; 1.0526x over previous
//
#include <hip/hip_runtime.h>
#include <climits>

#define HH 1024
#define WW 1024
#define DD 128
#define NPIX (HH * WW)
#define NSB 256    // stats blocks (4 rows each) in kA
#define NBB 1024   // main blocks (1 row each) in kB

// ws 4B-unit layout:
//   wsf[64..576)    M (4x128 row-major)
//   wsf[576..704)   c (128)
//   wsi[1024..1280) rminP | [1280..1536) rmaxP | [1536..1792) cminP
//   wsi[1792..2048) cmaxP | [2048..2304) cntP     (one per stats block)
//   wsf[8192..8192+128*1024) partials, layout [feature][block]
#define RMINP 1024
#define RMAXP 1280
#define CMINP 1536
#define CMAXP 1792
#define CNTP  2048
#define PART  8192

typedef __attribute__((ext_vector_type(2))) float f32x2;

// ---- stats for a block's 4 rows (proven rounds 4-12) -----------------------
__device__ __forceinline__ void d_stats(const float* __restrict__ x0, int blk,
                                        int tid, int* __restrict__ wsi,
                                        int (*sred)[8]) {
    const float4* x4 = (const float4*)(x0) + (size_t)blk * 1024;
    int any0, any1, any2, any3;
    int cmn = INT_MAX, cmx = -1, cnt = 0;
    int c4 = 4 * tid;
    {
        float4 v;
        bool z0, z1, z2, z3;
        #define STAT_K(K, ANY)                                                 \
            v = x4[K * 256 + tid];                                             \
            z0 = v.x != 0.f; z1 = v.y != 0.f; z2 = v.z != 0.f; z3 = v.w != 0.f;\
            ANY = (int)(z0 | z1 | z2 | z3);                                    \
            if (ANY) {                                                         \
                cmn = min(cmn, z0 ? c4 : (z1 ? c4+1 : (z2 ? c4+2 : c4+3)));    \
                cmx = max(cmx, z3 ? c4+3 : (z2 ? c4+2 : (z1 ? c4+1 : c4)));    \
            }                                                                  \
            cnt += (int)z0 + (int)z1 + (int)z2 + (int)z3;
        STAT_K(0, any0) STAT_K(1, any1) STAT_K(2, any2) STAT_K(3, any3)
        #undef STAT_K
    }
    for (int off = 32; off >= 1; off >>= 1) {
        cmn = min(cmn, __shfl_xor(cmn, off, 64));
        cmx = max(cmx, __shfl_xor(cmx, off, 64));
        cnt += __shfl_xor(cnt, off, 64);
        any0 |= __shfl_xor(any0, off, 64);
        any1 |= __shfl_xor(any1, off, 64);
        any2 |= __shfl_xor(any2, off, 64);
        any3 |= __shfl_xor(any3, off, 64);
    }
    int wave = tid >> 6;
    if ((tid & 63) == 0) {
        sred[wave][0] = cmn; sred[wave][1] = cmx; sred[wave][2] = cnt;
        sred[wave][3] = any0; sred[wave][4] = any1;
        sred[wave][5] = any2; sred[wave][6] = any3;
    }
    __syncthreads();
    if (tid == 0) {
        int a = sred[0][0], b = sred[0][1], c = sred[0][2];
        int f0 = sred[0][3], f1 = sred[0][4], f2 = sred[0][5], f3 = sred[0][6];
        for (int w = 1; w < 4; ++w) {
            a = min(a, sred[w][0]); b = max(b, sred[w][1]); c += sred[w][2];
            f0 |= sred[w][3]; f1 |= sred[w][4]; f2 |= sred[w][5]; f3 |= sred[w][6];
        }
        int r0 = blk * 4;
        wsi[RMINP + blk] = f0 ? r0 : (f1 ? r0+1 : (f2 ? r0+2 : (f3 ? r0+3 : INT_MAX)));
        wsi[RMAXP + blk] = f3 ? r0+3 : (f2 ? r0+2 : (f1 ? r0+1 : (f0 ? r0 : -1)));
        wsi[CMINP + blk] = a;
        wsi[CMAXP + blk] = b;
        wsi[CNTP  + blk] = c;
    }
}

// ---- kA: 256 stats blocks + 1 prep block (M, c, out = b3) ------------------
__global__ __launch_bounds__(256) void kA(const float* __restrict__ x0,
                                          const float* __restrict__ W1,
                                          const float* __restrict__ b1,
                                          const float* __restrict__ W2,
                                          const float* __restrict__ b2,
                                          const float* __restrict__ b3,
                                          float* __restrict__ out,
                                          float* __restrict__ wsf,
                                          int* __restrict__ wsi) {
    __shared__ int sred[4][8];
    int blk = blockIdx.x, tid = threadIdx.x;
    if (blk < NSB) { d_stats(x0, blk, tid, wsi, sred); return; }
    if (tid < 128) {
        int j = tid;
        float p0 = 0.f, p1 = 0.f, p2 = 0.f, p3 = 0.f, cc = 0.f;
        #pragma unroll 8
        for (int d = 0; d < DD; ++d) {
            float w2 = W2[d * DD + j];
            p0 = fmaf(W1[0 * DD + d], w2, p0);
            p1 = fmaf(W1[1 * DD + d], w2, p1);
            p2 = fmaf(W1[2 * DD + d], w2, p2);
            p3 = fmaf(W1[3 * DD + d], w2, p3);
            cc = fmaf(b1[d],          w2, cc);
        }
        wsf[64 + 0 * DD + j] = p0;
        wsf[64 + 1 * DD + j] = p1;
        wsf[64 + 2 * DD + j] = p2;
        wsf[64 + 3 * DD + j] = p3;
        wsf[576 + j] = cc + b2[j];
        out[j] = b3[j];              // seed output; kC accumulates atomically
    }
}

// ---- kB: main accumulate, NO LDS data path ---------------------------------
// 1 row/block. Wave w covers cols [w*256,(w+1)*256); lane l owns feats {l,l+64}.
// All lanes read the same float4 of x0/x1 (wave-uniform -> 1 txn, L1-resident).
// Zero pixels handled inline under a never-taken uniform branch.
__global__ __launch_bounds__(256) void kB(const float* __restrict__ x0,
                                          const float* __restrict__ x1,
                                          float* __restrict__ wsf,
                                          const int* __restrict__ wsi) {
    __shared__ int   sred[4][4];
    __shared__ float fred[4][132];         // [wave][feat], padded

    int tid = threadIdx.x, blk = blockIdx.x;
    int wv = tid >> 6, lane = tid & 63;

    // reduce the 256 stats partials (one per thread)
    int rmn = wsi[RMINP + tid], rmx = wsi[RMAXP + tid];
    int cmn = wsi[CMINP + tid], cmx = wsi[CMAXP + tid];
    for (int off = 32; off >= 1; off >>= 1) {
        rmn = min(rmn, __shfl_xor(rmn, off, 64));
        rmx = max(rmx, __shfl_xor(rmx, off, 64));
        cmn = min(cmn, __shfl_xor(cmn, off, 64));
        cmx = max(cmx, __shfl_xor(cmx, off, 64));
    }
    if (lane == 0) {
        sred[wv][0] = rmn; sred[wv][1] = rmx;
        sred[wv][2] = cmn; sred[wv][3] = cmx;
    }
    __syncthreads();
    rmn = min(min(sred[0][0], sred[1][0]), min(sred[2][0], sred[3][0]));
    rmx = max(max(sred[0][1], sred[1][1]), max(sred[2][1], sred[3][1]));
    cmn = min(min(sred[0][2], sred[1][2]), min(sred[2][2], sred[3][2]));
    cmx = max(max(sred[0][3], sred[1][3]), max(sred[2][3], sred[3][3]));

    int row = blk;
    int colbase = wv * 256;
    float rs = 1.0f / (float)(rmx - rmn);
    float cs = 1.0f / (float)(cmx - cmn);

    // coefficients for the lane's 2 features
    f32x2 M2v[2], M3v[2], tAv[2], tBv[2], stv[2], accA[2], accB[2];
    float a1s[2], rbs[2];
    #pragma unroll
    for (int k = 0; k < 2; ++k) {
        int f = lane + 64 * k;
        float M2 = wsf[64 + 2 * DD + f];
        float M3 = wsf[64 + 3 * DD + f];
        float a0 = wsf[64 + 0 * DD + f] * rs;
        float a1 = wsf[64 + 1 * DD + f] * cs;
        float cp = wsf[576 + f] - (float)rmn * a0 - (float)cmn * a1;
        float rb = fmaf((float)row, a0, cp);
        rbs[k] = rb; a1s[k] = a1;
        float t0 = fmaf((float)colbase, a1, rb);
        M2v[k] = (f32x2)M2;
        M3v[k] = (f32x2)M3;
        tAv[k].x = t0;            tAv[k].y = t0 + a1;          // px 0,1
        tBv[k].x = t0 + 2.f * a1; tBv[k].y = t0 + 3.f * a1;    // px 2,3
        stv[k] = (f32x2)(4.f * a1);
        accA[k] = (f32x2)0.f; accB[k] = (f32x2)0.f;
    }

    const float4* p0 = (const float4*)(x0 + (size_t)row * WW + colbase);
    const float4* p1 = (const float4*)(x1 + (size_t)row * WW + colbase);

    #pragma unroll 4
    for (int q = 0; q < 64; ++q) {
        float4 v0 = p0[q];        // wave-uniform address -> one transaction
        float4 v1 = p1[q];
        f32x2 v0A; v0A.x = v0.x; v0A.y = v0.y;
        f32x2 v0B; v0B.x = v0.z; v0B.y = v0.w;
        f32x2 v1A; v1A.x = v1.x; v1A.y = v1.y;
        f32x2 v1B; v1B.x = v1.z; v1B.y = v1.w;
        #pragma unroll
        for (int k = 0; k < 2; ++k) {
            f32x2 dA = __builtin_elementwise_fma(v0A, M2v[k],
                         __builtin_elementwise_fma(v1A, M3v[k], tAv[k]));
            f32x2 dB = __builtin_elementwise_fma(v0B, M2v[k],
                         __builtin_elementwise_fma(v1B, M3v[k], tBv[k]));
            accA[k] += __builtin_elementwise_max(dA, (f32x2)0.f);
            accB[k] += __builtin_elementwise_max(dB, (f32x2)0.f);
            tAv[k] += stv[k];
            tBv[k] += stv[k];
        }
        // masked-out (exact-zero) pixels: wave-uniform, essentially never taken
        if ((v0.x == 0.f) | (v0.y == 0.f) | (v0.z == 0.f) | (v0.w == 0.f)) {
            int col = colbase + 4 * q;
            #define SUBPX(VZ, V1C, CI)                                         \
                if (VZ == 0.f) {                                               \
                    _Pragma("unroll")                                          \
                    for (int k = 0; k < 2; ++k) {                              \
                        float tp = fmaf((float)(CI), a1s[k], rbs[k]);          \
                        accA[k].x -= fmaxf(fmaf(V1C, M3v[k].x, tp), 0.f);      \
                    }                                                          \
                }
            SUBPX(v0.x, v1.x, col + 0)
            SUBPX(v0.y, v1.y, col + 1)
            SUBPX(v0.z, v1.z, col + 2)
            SUBPX(v0.w, v1.w, col + 3)
            #undef SUBPX
        }
    }

    #pragma unroll
    for (int k = 0; k < 2; ++k) {
        f32x2 s = accA[k] + accB[k];
        fred[wv][lane + 64 * k] = s.x + s.y;
    }
    __syncthreads();
    if (tid < 128) {
        float s = (fred[0][tid] + fred[1][tid]) + (fred[2][tid] + fred[3][tid]);
        wsf[PART + (size_t)tid * NBB + blk] = s;
    }
}

// ---- kC: 128 blocks, one feature each: reduce + mean + matvec-atomics ------
__global__ __launch_bounds__(256) void kC(const float* __restrict__ wsf,
                                          const int* __restrict__ wsi,
                                          const float* __restrict__ W3,
                                          float* __restrict__ out) {
    __shared__ float sred[4];
    __shared__ int   cred[4];
    __shared__ float mf_sh;
    int f = blockIdx.x, tid = threadIdx.x;
    int wv = tid >> 6, lane = tid & 63;

    // total mask count (256 per-stats-block counts)
    int c = wsi[CNTP + tid];
    for (int off = 32; off >= 1; off >>= 1) c += __shfl_xor(c, off, 64);
    if (lane == 0) cred[wv] = c;

    // per-feature sum over 1024 block-partials (contiguous -> coalesced)
    const float4* p = (const float4*)(wsf + PART + (size_t)f * NBB);
    float4 v = p[tid];
    float S = (v.x + v.y) + (v.z + v.w);
    for (int off = 32; off >= 1; off >>= 1) S += __shfl_xor(S, off, 64);
    if (lane == 0) sred[wv] = S;
    __syncthreads();
    if (tid == 0) {
        float tot = (sred[0] + sred[1]) + (sred[2] + sred[3]);
        float cnt = (float)(cred[0] + cred[1] + cred[2] + cred[3]);
        mf_sh = tot / cnt;
    }
    __syncthreads();

    // out[j] += m_f * W3[f][j]  (row contiguous; 128 distinct addresses)
    if (tid < 128) {
        float mf = mf_sh;
        atomicAdd(&out[tid], mf * W3[f * DD + tid]);
    }
}

extern "C" void kernel_launch(void* const* d_in, const int* in_sizes, int n_in,
                              void* d_out, int out_size, void* d_ws, size_t ws_size,
                              hipStream_t stream) {
    const float* x  = (const float*)d_in[0];
    const float* x0 = x;
    const float* x1 = x + NPIX;
    const float* W1 = (const float*)d_in[1];
    const float* b1 = (const float*)d_in[2];
    const float* W2 = (const float*)d_in[3];
    const float* b2 = (const float*)d_in[4];
    const float* W3 = (const float*)d_in[5];
    const float* b3 = (const float*)d_in[6];
    float* outp = (float*)d_out;
    float* wsf  = (float*)d_ws;
    int*   wsi  = (int*)d_ws;

    hipLaunchKernelGGL(kA, dim3(NSB + 1), dim3(256), 0, stream,
                       x0, W1, b1, W2, b2, b3, outp, wsf, wsi);
    hipLaunchKernelGGL(kB, dim3(NBB), dim3(256), 0, stream, x0, x1, wsf, wsi);
    hipLaunchKernelGGL(kC, dim3(DD), dim3(256), 0, stream, wsf, wsi, W3, outp);
}

// Round 14
// 30.279 us; speedup vs baseline: 1.2773x; 1.2134x over previous
//
#include <hip/hip_runtime.h>
#include <climits>

#define HH 1024
#define WW 1024
#define DD 128
#define NPIX (HH * WW)
#define NSB 256    // stats blocks (4 rows each) in kA
#define NBB 1024   // main blocks (1 row each) in kB

// ws 4B-unit layout:
//   wsf[64..576)    M (4x128 row-major)
//   wsf[576..704)   c (128)
//   wsi[1024..1280) rminP | [1280..1536) rmaxP | [1536..1792) cminP
//   wsi[1792..2048) cmaxP | [2048..2304) cntP     (one per stats block)
//   wsf[6400..6656) x1-warm dummies
//   wsf[8192..8192+128*1024) partials, layout [feature][block]
#define RMINP 1024
#define RMAXP 1280
#define CMINP 1536
#define CMAXP 1792
#define CNTP  2048
#define PART  8192

typedef __attribute__((ext_vector_type(2))) float f32x2;

// ---- stats for a block's 4 rows (proven rounds 4-13) -----------------------
__device__ __forceinline__ void d_stats(const float* __restrict__ x0, int blk,
                                        int tid, int* __restrict__ wsi,
                                        int (*sred)[8]) {
    const float4* x4 = (const float4*)(x0) + (size_t)blk * 1024;
    int any0, any1, any2, any3;
    int cmn = INT_MAX, cmx = -1, cnt = 0;
    int c4 = 4 * tid;
    {
        float4 v;
        bool z0, z1, z2, z3;
        #define STAT_K(K, ANY)                                                 \
            v = x4[K * 256 + tid];                                             \
            z0 = v.x != 0.f; z1 = v.y != 0.f; z2 = v.z != 0.f; z3 = v.w != 0.f;\
            ANY = (int)(z0 | z1 | z2 | z3);                                    \
            if (ANY) {                                                         \
                cmn = min(cmn, z0 ? c4 : (z1 ? c4+1 : (z2 ? c4+2 : c4+3)));    \
                cmx = max(cmx, z3 ? c4+3 : (z2 ? c4+2 : (z1 ? c4+1 : c4)));    \
            }                                                                  \
            cnt += (int)z0 + (int)z1 + (int)z2 + (int)z3;
        STAT_K(0, any0) STAT_K(1, any1) STAT_K(2, any2) STAT_K(3, any3)
        #undef STAT_K
    }
    for (int off = 32; off >= 1; off >>= 1) {
        cmn = min(cmn, __shfl_xor(cmn, off, 64));
        cmx = max(cmx, __shfl_xor(cmx, off, 64));
        cnt += __shfl_xor(cnt, off, 64);
        any0 |= __shfl_xor(any0, off, 64);
        any1 |= __shfl_xor(any1, off, 64);
        any2 |= __shfl_xor(any2, off, 64);
        any3 |= __shfl_xor(any3, off, 64);
    }
    int wave = tid >> 6;
    if ((tid & 63) == 0) {
        sred[wave][0] = cmn; sred[wave][1] = cmx; sred[wave][2] = cnt;
        sred[wave][3] = any0; sred[wave][4] = any1;
        sred[wave][5] = any2; sred[wave][6] = any3;
    }
    __syncthreads();
    if (tid == 0) {
        int a = sred[0][0], b = sred[0][1], c = sred[0][2];
        int f0 = sred[0][3], f1 = sred[0][4], f2 = sred[0][5], f3 = sred[0][6];
        for (int w = 1; w < 4; ++w) {
            a = min(a, sred[w][0]); b = max(b, sred[w][1]); c += sred[w][2];
            f0 |= sred[w][3]; f1 |= sred[w][4]; f2 |= sred[w][5]; f3 |= sred[w][6];
        }
        int r0 = blk * 4;
        wsi[RMINP + blk] = f0 ? r0 : (f1 ? r0+1 : (f2 ? r0+2 : (f3 ? r0+3 : INT_MAX)));
        wsi[RMAXP + blk] = f3 ? r0+3 : (f2 ? r0+2 : (f1 ? r0+1 : (f0 ? r0 : -1)));
        wsi[CMINP + blk] = a;
        wsi[CMAXP + blk] = b;
        wsi[CNTP  + blk] = c;
    }
}

// ---- kA: 256 stats blocks (also warm x1 into L3) + 1 prep block ------------
__global__ __launch_bounds__(256) void kA(const float* __restrict__ x0,
                                          const float* __restrict__ x1,
                                          const float* __restrict__ W1,
                                          const float* __restrict__ b1,
                                          const float* __restrict__ W2,
                                          const float* __restrict__ b2,
                                          const float* __restrict__ b3,
                                          float* __restrict__ out,
                                          float* __restrict__ wsf,
                                          int* __restrict__ wsi) {
    __shared__ int sred[4][8];
    int blk = blockIdx.x, tid = threadIdx.x;
    if (blk < NSB) {
        d_stats(x0, blk, tid, wsi, sred);
        // warm this block's x1 rows into L3 (kB's staging then avoids HBM miss)
        const float4* y4 = (const float4*)(x1) + (size_t)blk * 1024;
        float s = 0.f;
        #pragma unroll
        for (int k = 0; k < 4; ++k) {
            float4 t4 = y4[k * 256 + tid];
            s += (t4.x + t4.y) + (t4.z + t4.w);
        }
        if (tid == 0) wsf[6400 + blk] = s;   // keep warm loads live
        return;
    }
    if (tid < 128) {
        int j = tid;
        float p0 = 0.f, p1 = 0.f, p2 = 0.f, p3 = 0.f, cc = 0.f;
        #pragma unroll 8
        for (int d = 0; d < DD; ++d) {
            float w2 = W2[d * DD + j];
            p0 = fmaf(W1[0 * DD + d], w2, p0);
            p1 = fmaf(W1[1 * DD + d], w2, p1);
            p2 = fmaf(W1[2 * DD + d], w2, p2);
            p3 = fmaf(W1[3 * DD + d], w2, p3);
            cc = fmaf(b1[d],          w2, cc);
        }
        wsf[64 + 0 * DD + j] = p0;
        wsf[64 + 1 * DD + j] = p1;
        wsf[64 + 2 * DD + j] = p2;
        wsf[64 + 3 * DD + j] = p3;
        wsf[576 + j] = cc + b2[j];
        out[j] = b3[j];              // seed output; kC accumulates atomically
    }
}

// ---- kB: main accumulate, 1 row/block, 4 features/thread, packed-f32 -------
// LDS layout per float4: (v0@px0, v0@px1, v1@px0, v1@px1) -> aligned f32 pairs
// for v_pk_fma_f32. Thread (ft=tid&31, cq=tid>>5): features {ft+32k},
// col-eighth cq (128 px = 64 pairs). Register-prefetch software pipeline.
__global__ __launch_bounds__(256) void kB(const float* __restrict__ x0,
                                          const float* __restrict__ x1,
                                          float* __restrict__ wsf,
                                          const int* __restrict__ wsi) {
    __shared__ float sv_f[4096];           // de-interleaved pairs, 1 row
    __shared__ unsigned short lidx[1024];
    __shared__ int   lcnt;
    __shared__ int   sred[4][4];
    __shared__ float fred[128][9];         // +1 pad -> stride 9, conflict-free

    int tid = threadIdx.x, blk = blockIdx.x;
    int wv = tid >> 6, lane = tid & 63;

    if (tid == 0) lcnt = 0;

    // reduce the 256 stats partials (one per thread)
    int rmn = wsi[RMINP + tid], rmx = wsi[RMAXP + tid];
    int cmn = wsi[CMINP + tid], cmx = wsi[CMAXP + tid];
    for (int off = 32; off >= 1; off >>= 1) {
        rmn = min(rmn, __shfl_xor(rmn, off, 64));
        rmx = max(rmx, __shfl_xor(rmx, off, 64));
        cmn = min(cmn, __shfl_xor(cmn, off, 64));
        cmx = max(cmx, __shfl_xor(cmx, off, 64));
    }
    if (lane == 0) {
        sred[wv][0] = rmn; sred[wv][1] = rmx;
        sred[wv][2] = cmn; sred[wv][3] = cmx;
    }
    __syncthreads();   // sred + lcnt visible
    rmn = min(min(sred[0][0], sred[1][0]), min(sred[2][0], sred[3][0]));
    rmx = max(max(sred[0][1], sred[1][1]), max(sred[2][1], sred[3][1]));
    cmn = min(min(sred[0][2], sred[1][2]), min(sred[2][2], sred[3][2]));
    cmx = max(max(sred[0][3], sred[1][3]), max(sred[2][3], sred[3][3]));

    // stage this row de-interleaved; record exact-zero pixels (rare)
    const float4* x04 = (const float4*)(x0) + (size_t)blk * 256;
    const float4* x14 = (const float4*)(x1) + (size_t)blk * 256;
    float4* sv4 = (float4*)sv_f;
    {
        float4 va = x04[tid];
        float4 vb = x14[tid];
        sv4[2 * tid]     = make_float4(va.x, va.y, vb.x, vb.y);
        sv4[2 * tid + 1] = make_float4(va.z, va.w, vb.z, vb.w);
        int p4 = 4 * tid;
        if (va.x == 0.f) { int p = atomicAdd(&lcnt, 1); lidx[p] = (unsigned short)(p4 + 0); }
        if (va.y == 0.f) { int p = atomicAdd(&lcnt, 1); lidx[p] = (unsigned short)(p4 + 1); }
        if (va.z == 0.f) { int p = atomicAdd(&lcnt, 1); lidx[p] = (unsigned short)(p4 + 2); }
        if (va.w == 0.f) { int p = atomicAdd(&lcnt, 1); lidx[p] = (unsigned short)(p4 + 3); }
    }
    __syncthreads();

    int ft = tid & 31;         // feature group: ft, ft+32, ft+64, ft+96
    int cq = tid >> 5;         // col eighth (128 px)
    int row = blk;
    float rs = 1.0f / (float)(rmx - rmn);
    float cs = 1.0f / (float)(cmx - cmn);

    f32x2 M2v[4], M3v[4], tv[4], st[4], acc[4];
    float a1v[4], rb[4];
    float accsub[4];
    #pragma unroll
    for (int k = 0; k < 4; ++k) {
        int f = ft + 32 * k;
        float M2 = wsf[64 + 2 * DD + f];
        float M3 = wsf[64 + 3 * DD + f];
        float a0 = wsf[64 + 0 * DD + f] * rs;
        float a1 = wsf[64 + 1 * DD + f] * cs;
        float cp = wsf[576 + f] - (float)rmn * a0 - (float)cmn * a1;
        rb[k]  = fmaf((float)row, a0, cp);
        a1v[k] = a1;
        float tA = fmaf((float)(cq * 128), a1, rb[k]);
        M2v[k] = (f32x2)M2;
        M3v[k] = (f32x2)M3;
        tv[k].x = tA; tv[k].y = tA + a1;
        st[k] = (f32x2)(a1 + a1);
        acc[k] = (f32x2)0.f;
        accsub[k] = 0.f;
    }

    const float4* p = sv4 + cq * 64;
    float4 vq = p[0];                       // software-pipelined LDS read
    #pragma unroll 4
    for (int q = 0; q < 64; ++q) {
        float4 vn = p[(q + 1) & 63];        // prefetch next (wraps, harmless)
        f32x2 v0; v0.x = vq.x; v0.y = vq.y;
        f32x2 v1; v1.x = vq.z; v1.y = vq.w;
        #pragma unroll
        for (int k = 0; k < 4; ++k) {
            f32x2 d = __builtin_elementwise_fma(v0, M2v[k],
                        __builtin_elementwise_fma(v1, M3v[k], tv[k]));
            f32x2 r = __builtin_elementwise_max(d, (f32x2)0.f);
            acc[k] += r;           // v_pk_add_f32
            tv[k] += st[k];        // v_pk_add_f32
        }
        vq = vn;
    }

    int nz = lcnt;             // subtract masked-out (zero) pixels
    for (int ii = 0; ii < nz; ++ii) {
        int px = lidx[ii];
        if ((px >> 7) == cq) {
            float v0 = sv_f[(px >> 1) * 4 + (px & 1)];
            float v1 = sv_f[(px >> 1) * 4 + 2 + (px & 1)];
            #pragma unroll
            for (int k = 0; k < 4; ++k) {
                float tp = fmaf((float)px, a1v[k], rb[k]);
                accsub[k] += fmaxf(fmaf(v0, M2v[k].x, fmaf(v1, M3v[k].x, tp)), 0.f);
            }
        }
    }

    #pragma unroll
    for (int k = 0; k < 4; ++k)
        fred[ft + 32 * k][cq] = (acc[k].x + acc[k].y) - accsub[k];
    __syncthreads();
    if (tid < 128) {
        const float* fr = fred[tid];
        float s = ((fr[0] + fr[1]) + (fr[2] + fr[3]))
                + ((fr[4] + fr[5]) + (fr[6] + fr[7]));
        wsf[PART + (size_t)tid * NBB + blk] = s;
    }
}

// ---- kC: 128 blocks, one feature each: reduce + mean + matvec-atomics ------
__global__ __launch_bounds__(256) void kC(const float* __restrict__ wsf,
                                          const int* __restrict__ wsi,
                                          const float* __restrict__ W3,
                                          float* __restrict__ out) {
    __shared__ float sred[4];
    __shared__ int   cred[4];
    __shared__ float mf_sh;
    int f = blockIdx.x, tid = threadIdx.x;
    int wv = tid >> 6, lane = tid & 63;

    // total mask count (256 per-stats-block counts)
    int c = wsi[CNTP + tid];
    for (int off = 32; off >= 1; off >>= 1) c += __shfl_xor(c, off, 64);
    if (lane == 0) cred[wv] = c;

    // per-feature sum over 1024 block-partials (contiguous -> coalesced)
    const float4* p = (const float4*)(wsf + PART + (size_t)f * NBB);
    float4 v = p[tid];
    float S = (v.x + v.y) + (v.z + v.w);
    for (int off = 32; off >= 1; off >>= 1) S += __shfl_xor(S, off, 64);
    if (lane == 0) sred[wv] = S;
    __syncthreads();
    if (tid == 0) {
        float tot = (sred[0] + sred[1]) + (sred[2] + sred[3]);
        float cnt = (float)(cred[0] + cred[1] + cred[2] + cred[3]);
        mf_sh = tot / cnt;
    }
    __syncthreads();

    // out[j] += m_f * W3[f][j]  (row contiguous; 128 distinct addresses)
    if (tid < 128) {
        float mf = mf_sh;
        atomicAdd(&out[tid], mf * W3[f * DD + tid]);
    }
}

extern "C" void kernel_launch(void* const* d_in, const int* in_sizes, int n_in,
                              void* d_out, int out_size, void* d_ws, size_t ws_size,
                              hipStream_t stream) {
    const float* x  = (const float*)d_in[0];
    const float* x0 = x;
    const float* x1 = x + NPIX;
    const float* W1 = (const float*)d_in[1];
    const float* b1 = (const float*)d_in[2];
    const float* W2 = (const float*)d_in[3];
    const float* b2 = (const float*)d_in[4];
    const float* W3 = (const float*)d_in[5];
    const float* b3 = (const float*)d_in[6];
    float* outp = (float*)d_out;
    float* wsf  = (float*)d_ws;
    int*   wsi  = (int*)d_ws;

    hipLaunchKernelGGL(kA, dim3(NSB + 1), dim3(256), 0, stream,
                       x0, x1, W1, b1, W2, b2, b3, outp, wsf, wsi);
    hipLaunchKernelGGL(kB, dim3(NBB), dim3(256), 0, stream, x0, x1, wsf, wsi);
    hipLaunchKernelGGL(kC, dim3(DD), dim3(256), 0, stream, wsf, wsi, W3, outp);
}